// Round 1
// baseline (154.061 us; speedup 1.0000x reference)
//
#include <hip/hip_runtime.h>

#define F_DIM 64
#define H_DIM 64
#define B_TOTAL 16384
#define FC 8            // features per block (y-partials)
#define NFC (F_DIM/FC)  // 8 f-chunks
#define NEG_SLOPE 0.01f

// ws layout in floats
#define W1OFF   0        // F*H*H = 262144
#define W0OFF   262144   // F*H  = 4096
#define B0OFF   266240   // 4096
#define B1OFF   270336   // 4096
#define W2OFF   274432   // 4096
#define B2OFF   278528   // 64
#define YPOFF   278592   // NFC*B = 131072
#define KLPOFF  409664   // 64
#define KL_NTOT 278592
#define KL_NBLK 64

// KL constant: ln(0.1) - 0.5
#define KL_C (-2.8025850929940457f)

__global__ void bayesnam_prep(const float* __restrict__ wmu0, const float* __restrict__ wls0,
                              const float* __restrict__ bmu0, const float* __restrict__ bls0,
                              const float* __restrict__ ew0,  const float* __restrict__ eb0,
                              const float* __restrict__ wmu1, const float* __restrict__ wls1,
                              const float* __restrict__ bmu1, const float* __restrict__ bls1,
                              const float* __restrict__ ew1,  const float* __restrict__ eb1,
                              const float* __restrict__ wmu2, const float* __restrict__ wls2,
                              const float* __restrict__ bmu2, const float* __restrict__ bls2,
                              const float* __restrict__ ew2,  const float* __restrict__ eb2,
                              float* __restrict__ ws) {
    __shared__ float red[256];
    const int tid = threadIdx.x;
    float klacc = 0.f;
    for (int idx = blockIdx.x * 256 + tid; idx < KL_NTOT; idx += KL_NBLK * 256) {
        const float *mu, *ls, *ew;
        float scale;
        int j, effoff;
        if (idx < 4096)        { j = idx;          mu = wmu0; ls = wls0; ew = ew0; scale = 0.015625f;       effoff = W0OFF; }
        else if (idx < 8192)   { j = idx - 4096;   mu = bmu0; ls = bls0; ew = eb0; scale = 0.015625f;       effoff = B0OFF; }
        else if (idx < 270336) { j = idx - 8192;   mu = wmu1; ls = wls1; ew = ew1; scale = 0.000244140625f; effoff = W1OFF; }
        else if (idx < 274432) { j = idx - 270336; mu = bmu1; ls = bls1; ew = eb1; scale = 0.015625f;       effoff = B1OFF; }
        else if (idx < 278528) { j = idx - 274432; mu = wmu2; ls = wls2; ew = ew2; scale = 0.015625f;       effoff = W2OFF; }
        else                   { j = idx - 278528; mu = bmu2; ls = bls2; ew = eb2; scale = 1.0f;            effoff = B2OFF; }
        const float m = mu[j];
        const float l = ls[j];
        const float e = ew[j];
        const float ex = expf(l);
        ws[effoff + j] = fmaf(ex, e, m);               // effective parameter
        klacc += scale * ((KL_C - l) + 50.f * fmaf(ex, ex, m * m));
    }
    red[tid] = klacc;
    __syncthreads();
    for (int s = 128; s > 0; s >>= 1) {
        if (tid < s) red[tid] += red[tid + s];
        __syncthreads();
    }
    if (tid == 0) ws[KLPOFF + blockIdx.x] = red[0];
}

__global__ __launch_bounds__(256, 2) void bayesnam_main(const float* __restrict__ fin,
                                                        const float* __restrict__ ws,
                                                        float* __restrict__ ypart) {
    __shared__ float W1t[H_DIM * H_DIM];
    __shared__ float w0r[H_DIM], b0r[H_DIM], b1r[H_DIM], w2r[H_DIM];
    __shared__ float b2s;
    const int tid = threadIdx.x;
    const int b = blockIdx.x * 256 + tid;
    const int fbase = blockIdx.y * FC;
    float yacc = 0.f;

    for (int fi = 0; fi < FC; ++fi) {
        const int f = fbase + fi;
        __syncthreads();   // protect previous iteration's LDS reads
        // stage W1eff[f] (64x64) into LDS, coalesced float4
        {
            const float4* src = (const float4*)(ws + (size_t)f * H_DIM * H_DIM);
            float4* dst = (float4*)W1t;
            #pragma unroll
            for (int k = 0; k < 4; ++k) dst[tid + k * 256] = src[tid + k * 256];
        }
        if (tid < 64)        w0r[tid]        = ws[W0OFF + f * 64 + tid];
        else if (tid < 128)  b0r[tid - 64]   = ws[B0OFF + f * 64 + (tid - 64)];
        else if (tid < 192)  b1r[tid - 128]  = ws[B1OFF + f * 64 + (tid - 128)];
        else                 w2r[tid - 192]  = ws[W2OFF + f * 64 + (tid - 192)];
        if (tid == 0) b2s = ws[B2OFF + f];
        __syncthreads();

        const float xf = fin[(size_t)b * F_DIM + f];

        // layer 0: h0[o] = leaky(xf * W0[o] + b0[o])
        float h0[H_DIM];
        #pragma unroll
        for (int o = 0; o < H_DIM; ++o) {
            float v = fmaf(xf, w0r[o], b0r[o]);
            h0[o] = v > 0.f ? v : NEG_SLOPE * v;
        }

        // layer 1 + leaky + layer 2 dot
        float s = b2s;
        const float4* W1v = (const float4*)W1t;
        const float4* b1v = (const float4*)b1r;
        const float4* w2v = (const float4*)w2r;
        for (int og = 0; og < 16; ++og) {
            float4 acc = b1v[og];
            #pragma unroll
            for (int i = 0; i < H_DIM; ++i) {
                const float4 w = W1v[i * 16 + og];
                acc.x = fmaf(h0[i], w.x, acc.x);
                acc.y = fmaf(h0[i], w.y, acc.y);
                acc.z = fmaf(h0[i], w.z, acc.z);
                acc.w = fmaf(h0[i], w.w, acc.w);
            }
            const float4 wv = w2v[og];
            float hx = acc.x > 0.f ? acc.x : NEG_SLOPE * acc.x;
            float hy = acc.y > 0.f ? acc.y : NEG_SLOPE * acc.y;
            float hz = acc.z > 0.f ? acc.z : NEG_SLOPE * acc.z;
            float hw = acc.w > 0.f ? acc.w : NEG_SLOPE * acc.w;
            s = fmaf(hx, wv.x, s);
            s = fmaf(hy, wv.y, s);
            s = fmaf(hz, wv.z, s);
            s = fmaf(hw, wv.w, s);
        }
        yacc += s;
    }
    ypart[(size_t)blockIdx.y * B_TOTAL + b] = yacc;
}

__global__ void bayesnam_finish(const float* __restrict__ ws, const float* __restrict__ bias,
                                float* __restrict__ out) {
    const int b = blockIdx.x * 256 + threadIdx.x;
    float acc = bias[0];
    #pragma unroll
    for (int c = 0; c < NFC; ++c) acc += ws[YPOFF + c * B_TOTAL + b];
    out[b] = acc;
    if (blockIdx.x == 0 && threadIdx.x == 0) {
        float k = 0.f;
        for (int i = 0; i < KL_NBLK; ++i) k += ws[KLPOFF + i];
        out[B_TOTAL] = k;
    }
}

extern "C" void kernel_launch(void* const* d_in, const int* in_sizes, int n_in,
                              void* d_out, int out_size, void* d_ws, size_t ws_size,
                              hipStream_t stream) {
    const float* fin  = (const float*)d_in[0];
    const float* wmu0 = (const float*)d_in[1];
    const float* wls0 = (const float*)d_in[2];
    const float* bmu0 = (const float*)d_in[3];
    const float* bls0 = (const float*)d_in[4];
    const float* ew0  = (const float*)d_in[5];
    const float* eb0  = (const float*)d_in[6];
    const float* wmu1 = (const float*)d_in[7];
    const float* wls1 = (const float*)d_in[8];
    const float* bmu1 = (const float*)d_in[9];
    const float* bls1 = (const float*)d_in[10];
    const float* ew1  = (const float*)d_in[11];
    const float* eb1  = (const float*)d_in[12];
    const float* wmu2 = (const float*)d_in[13];
    const float* wls2 = (const float*)d_in[14];
    const float* bmu2 = (const float*)d_in[15];
    const float* bls2 = (const float*)d_in[16];
    const float* ew2  = (const float*)d_in[17];
    const float* eb2  = (const float*)d_in[18];
    const float* bias = (const float*)d_in[19];

    float* ws  = (float*)d_ws;
    float* out = (float*)d_out;

    hipLaunchKernelGGL(bayesnam_prep, dim3(KL_NBLK), dim3(256), 0, stream,
                       wmu0, wls0, bmu0, bls0, ew0, eb0,
                       wmu1, wls1, bmu1, bls1, ew1, eb1,
                       wmu2, wls2, bmu2, bls2, ew2, eb2, ws);

    hipLaunchKernelGGL(bayesnam_main, dim3(B_TOTAL / 256, NFC), dim3(256), 0, stream,
                       fin, ws, ws + YPOFF);

    hipLaunchKernelGGL(bayesnam_finish, dim3(B_TOTAL / 256), dim3(256), 0, stream,
                       ws, bias, out);
}

// Round 2
// 44.579 us; speedup vs baseline: 3.4559x; 3.4559x over previous
//
#include <hip/hip_runtime.h>

typedef short short8 __attribute__((ext_vector_type(8)));
typedef float floatx4 __attribute__((ext_vector_type(4)));

#define NEG 0.01f
#define KL_C (-2.8025850929940457f)

// ws layout (float units)
#define W1BF_FLOATS 131072   // 262144 bf16 fragments, offset 0
#define W0OFF  131072
#define B0OFF  135168
#define B1OFF  139264
#define W2OFF  143360
#define B2OFF  147456
#define KLPOFF 147520        // 64
#define YPOFF  147584        // 8 * 16384
#define KL_NTOT 278592

__device__ __forceinline__ unsigned bfbits(float x) {
    union { float f; unsigned u; } v; v.f = x;
    return (v.u + 0x7fffu + ((v.u >> 16) & 1u)) >> 16;   // RNE bf16
}
__device__ __forceinline__ unsigned pack2(float lo, float hi) {
    return bfbits(lo) | (bfbits(hi) << 16);
}

// Role-split prep: blocks 0..63 = KL partials + small effective params (fp32);
// blocks 64..127 = per-feature W1 effective weights -> bf16 MFMA B-fragments.
__global__ void bayesnam_prep(const float* __restrict__ wmu0, const float* __restrict__ wls0,
                              const float* __restrict__ bmu0, const float* __restrict__ bls0,
                              const float* __restrict__ ew0,  const float* __restrict__ eb0,
                              const float* __restrict__ wmu1, const float* __restrict__ wls1,
                              const float* __restrict__ bmu1, const float* __restrict__ bls1,
                              const float* __restrict__ ew1,  const float* __restrict__ eb1,
                              const float* __restrict__ wmu2, const float* __restrict__ wls2,
                              const float* __restrict__ bmu2, const float* __restrict__ bls2,
                              const float* __restrict__ ew2,  const float* __restrict__ eb2,
                              float* __restrict__ ws) {
    const int tid = threadIdx.x;
    if (blockIdx.x < 64) {
        __shared__ float red[256];
        float klacc = 0.f;
        for (int idx = blockIdx.x * 256 + tid; idx < KL_NTOT; idx += 64 * 256) {
            const float *mu, *ls, *ew;
            float scale;
            int j, effoff;
            if (idx < 4096)        { j = idx;          mu = wmu0; ls = wls0; ew = ew0; scale = 0.015625f;       effoff = W0OFF; }
            else if (idx < 8192)   { j = idx - 4096;   mu = bmu0; ls = bls0; ew = eb0; scale = 0.015625f;       effoff = B0OFF; }
            else if (idx < 270336) { j = idx - 8192;   mu = wmu1; ls = wls1; ew = ew1; scale = 0.000244140625f; effoff = -1;    }
            else if (idx < 274432) { j = idx - 270336; mu = bmu1; ls = bls1; ew = eb1; scale = 0.015625f;       effoff = B1OFF; }
            else if (idx < 278528) { j = idx - 274432; mu = wmu2; ls = wls2; ew = ew2; scale = 0.015625f;       effoff = W2OFF; }
            else                   { j = idx - 278528; mu = bmu2; ls = bls2; ew = eb2; scale = 1.0f;            effoff = B2OFF; }
            const float m = mu[j];
            const float l = ls[j];
            const float ex = expf(l);
            if (effoff >= 0) ws[effoff + j] = fmaf(ex, ew[j], m);
            klacc += scale * ((KL_C - l) + 50.f * fmaf(ex, ex, m * m));
        }
        red[tid] = klacc;
        __syncthreads();
        for (int s = 128; s > 0; s >>= 1) {
            if (tid < s) red[tid] += red[tid + s];
            __syncthreads();
        }
        if (tid == 0) ws[KLPOFF + blockIdx.x] = red[0];
    } else {
        // B-fragment builder for feature f: layout [f][kk][n][lane][j(8 bf16)]
        __shared__ float w1s[64 * 65];
        const int f = blockIdx.x - 64;
        const size_t base = (size_t)f * 4096;
        for (int i = 0; i < 16; ++i) {
            const int idx = i * 256 + tid;              // idx = k*64 + col
            const int k = idx >> 6, col = idx & 63;
            const float m = wmu1[base + idx];
            const float l = wls1[base + idx];
            const float e = ew1[base + idx];
            w1s[k * 65 + col] = fmaf(expf(l), e, m);
        }
        __syncthreads();
        uint4* outp = (uint4*)((char*)ws + (size_t)f * 8192);
        for (int it = 0; it < 2; ++it) {
            const int g = it * 256 + tid;               // 0..511 = kk*256 + n*64 + lane
            const int lane = g & 63;
            const int n = (g >> 6) & 3;
            const int kk = g >> 8;
            const int k0 = kk * 32 + ((lane >> 4) << 3);
            const int col = n * 16 + (lane & 15);
            float v[8];
            #pragma unroll
            for (int j = 0; j < 8; ++j) v[j] = w1s[(k0 + j) * 65 + col];
            uint4 o;
            o.x = pack2(v[0], v[1]); o.y = pack2(v[2], v[3]);
            o.z = pack2(v[4], v[5]); o.w = pack2(v[6], v[7]);
            outp[g] = o;
        }
    }
}

// Main: per wave 32 batch rows x 64 hidden, iterate 8 features of the chunk.
// No LDS, no barriers. MFMA 16x16x32 bf16, fp32 epilogue.
__global__ __launch_bounds__(256, 4) void bayesnam_main(const float* __restrict__ fin,
                                                        const float* __restrict__ ws,
                                                        float* __restrict__ ypart) {
    const int tid = threadIdx.x;
    const int l   = tid & 63;
    const int wid = tid >> 6;
    const int l15 = l & 15;
    const int lg  = l >> 4;                       // 0..3
    const int rowbase = blockIdx.x * 128 + wid * 32;
    const int fc = blockIdx.y;
    const int f0 = fc * 8;

    const uint4* __restrict__ w1q = (const uint4*)ws;

    floatx4 acc[2][4];
    float yacc[2][4];
    #pragma unroll
    for (int r = 0; r < 2; ++r)
        #pragma unroll
        for (int q = 0; q < 4; ++q) yacc[r][q] = 0.f;
    float b2sum = 0.f;

    const float* xp0 = fin + (size_t)(rowbase + l15) * 64 + f0;
    const float* xp1 = fin + (size_t)(rowbase + 16 + l15) * 64 + f0;

    #pragma unroll 1
    for (int fi = 0; fi < 8; ++fi) {
        const int f = f0 + fi;
        const float* w0p = ws + W0OFF + f * 64;
        const float* b0p = ws + B0OFF + f * 64;
        const float* b1p = ws + B1OFF + f * 64;
        const float* w2p = ws + W2OFF + f * 64;

        // init accumulators with b1 (broadcast across rows)
        #pragma unroll
        for (int n = 0; n < 4; ++n) {
            const float bv = b1p[n * 16 + l15];
            acc[0][n] = floatx4{bv, bv, bv, bv};
            acc[1][n] = floatx4{bv, bv, bv, bv};
        }

        const float x0 = xp0[fi];
        const float x1 = xp1[fi];

        #pragma unroll
        for (int kk = 0; kk < 2; ++kk) {
            const int kb = kk * 32 + lg * 8;
            const floatx4 w0a = *(const floatx4*)(w0p + kb);
            const floatx4 w0b = *(const floatx4*)(w0p + kb + 4);
            const floatx4 b0a = *(const floatx4*)(b0p + kb);
            const floatx4 b0b = *(const floatx4*)(b0p + kb + 4);

            short8 a0, a1;
            #pragma unroll
            for (int j = 0; j < 4; ++j) {
                float h = fmaf(x0, w0a[j], b0a[j]); h = fmaxf(h, NEG * h);
                a0[j] = (short)bfbits(h);
                h = fmaf(x1, w0a[j], b0a[j]); h = fmaxf(h, NEG * h);
                a1[j] = (short)bfbits(h);
                h = fmaf(x0, w0b[j], b0b[j]); h = fmaxf(h, NEG * h);
                a0[j + 4] = (short)bfbits(h);
                h = fmaf(x1, w0b[j], b0b[j]); h = fmaxf(h, NEG * h);
                a1[j + 4] = (short)bfbits(h);
            }

            const uint4* bp = w1q + (size_t)(f * 8 + kk * 4) * 64 + l;
            short8 bfr[4];
            #pragma unroll
            for (int n = 0; n < 4; ++n) {
                const uint4 t = bp[n * 64];
                bfr[n] = *(const short8*)&t;
            }
            #pragma unroll
            for (int n = 0; n < 4; ++n) {
                acc[0][n] = __builtin_amdgcn_mfma_f32_16x16x32_bf16(a0, bfr[n], acc[0][n], 0, 0, 0);
                acc[1][n] = __builtin_amdgcn_mfma_f32_16x16x32_bf16(a1, bfr[n], acc[1][n], 0, 0, 0);
            }
        }

        // epilogue: leaky + dot with w2 (fp32)
        #pragma unroll
        for (int n = 0; n < 4; ++n) {
            const float w2v = w2p[n * 16 + l15];
            #pragma unroll
            for (int r = 0; r < 2; ++r)
                #pragma unroll
                for (int q = 0; q < 4; ++q) {
                    float v = acc[r][n][q];
                    v = fmaxf(v, NEG * v);
                    yacc[r][q] = fmaf(v, w2v, yacc[r][q]);
                }
        }
        b2sum += ws[B2OFF + f];
    }

    // reduce over the 16 column-lanes (C layout: col = l&15, row = lg*4+q)
    #pragma unroll
    for (int r = 0; r < 2; ++r)
        #pragma unroll
        for (int q = 0; q < 4; ++q) {
            float v = yacc[r][q];
            v += __shfl_xor(v, 1, 64);
            v += __shfl_xor(v, 2, 64);
            v += __shfl_xor(v, 4, 64);
            v += __shfl_xor(v, 8, 64);
            yacc[r][q] = v;
        }
    if (l15 == 0) {
        float* yp = ypart + (size_t)fc * 16384 + rowbase;
        #pragma unroll
        for (int r = 0; r < 2; ++r)
            #pragma unroll
            for (int q = 0; q < 4; ++q)
                yp[r * 16 + lg * 4 + q] = yacc[r][q] + b2sum;
    }
}

__global__ void bayesnam_finish(const float* __restrict__ ws, const float* __restrict__ bias,
                                float* __restrict__ out) {
    const int b = blockIdx.x * 256 + threadIdx.x;
    float acc = bias[0];
    #pragma unroll
    for (int c = 0; c < 8; ++c) acc += ws[YPOFF + c * 16384 + b];
    out[b] = acc;
    if (blockIdx.x == 0 && threadIdx.x == 0) {
        float k = 0.f;
        for (int i = 0; i < 64; ++i) k += ws[KLPOFF + i];
        out[16384] = k;
    }
}

extern "C" void kernel_launch(void* const* d_in, const int* in_sizes, int n_in,
                              void* d_out, int out_size, void* d_ws, size_t ws_size,
                              hipStream_t stream) {
    const float* fin  = (const float*)d_in[0];
    const float* wmu0 = (const float*)d_in[1];
    const float* wls0 = (const float*)d_in[2];
    const float* bmu0 = (const float*)d_in[3];
    const float* bls0 = (const float*)d_in[4];
    const float* ew0  = (const float*)d_in[5];
    const float* eb0  = (const float*)d_in[6];
    const float* wmu1 = (const float*)d_in[7];
    const float* wls1 = (const float*)d_in[8];
    const float* bmu1 = (const float*)d_in[9];
    const float* bls1 = (const float*)d_in[10];
    const float* ew1  = (const float*)d_in[11];
    const float* eb1  = (const float*)d_in[12];
    const float* wmu2 = (const float*)d_in[13];
    const float* wls2 = (const float*)d_in[14];
    const float* bmu2 = (const float*)d_in[15];
    const float* bls2 = (const float*)d_in[16];
    const float* ew2  = (const float*)d_in[17];
    const float* eb2  = (const float*)d_in[18];
    const float* bias = (const float*)d_in[19];

    float* ws  = (float*)d_ws;
    float* out = (float*)d_out;

    hipLaunchKernelGGL(bayesnam_prep, dim3(128), dim3(256), 0, stream,
                       wmu0, wls0, bmu0, bls0, ew0, eb0,
                       wmu1, wls1, bmu1, bls1, ew1, eb1,
                       wmu2, wls2, bmu2, bls2, ew2, eb2, ws);

    hipLaunchKernelGGL(bayesnam_main, dim3(128, 8), dim3(256), 0, stream,
                       fin, ws, ws + YPOFF);

    hipLaunchKernelGGL(bayesnam_finish, dim3(64), dim3(256), 0, stream,
                       ws, bias, out);
}